// Round 16
// baseline (58.955 us; speedup 1.0000x reference)
//
#include <hip/hip_runtime.h>

#define BB 32
#define NN 1024
#define MM 1024
#define DD 128
#define PACK_BLOCKS (BB * NN / 4)   // 8192 blocks, wave-per-row
#define PREP_BLOCKS (BB * (MM / 64))

typedef __attribute__((ext_vector_type(4))) float f32x4;
typedef __attribute__((ext_vector_type(8))) __bf16 bf16x8;
typedef unsigned short ushort_t;
typedef unsigned int uint_t;

#define L2E 1.44269504f
#define KEXP 9.357623e-14f      // exp(-30): folded softmax shift (cancels in deg/Z)

__device__ __forceinline__ unsigned f2bf(float x) {
    unsigned u = __builtin_bit_cast(unsigned, x);
    return (u + 0x7fffu + ((u >> 16) & 1u)) >> 16;  // RNE bf16, finite inputs
}

// async global->LDS, 16 B per lane; dest must be linear (base + lane*16)
#define GLOAD16(gp, lp)                                                     \
    __builtin_amdgcn_global_load_lds(                                       \
        (const __attribute__((address_space(1))) unsigned int*)(gp),        \
        (__attribute__((address_space(3))) unsigned int*)(lp), 16, 0, 0)

// ---- Kernel 1 (role-split): pack: adj -> swizzled bitmask + deg ; e1 = h·a1
//                             prep: gq = bf16(g)^T tiles ; e2 = g·a2 ---------
// pack streams adj CONTIGUOUSLY (4 KB/row/wave) at full HBM rate.
__global__ __launch_bounds__(256) void pack_prep(
    const int* __restrict__ adj, const float* __restrict__ h,
    const float* __restrict__ g,
    const float* __restrict__ a1, const float* __restrict__ a2,
    uint_t* __restrict__ maskw, float* __restrict__ degf,
    float* __restrict__ e1, ushort_t* __restrict__ gq,
    float* __restrict__ e2)
{
    __shared__ ushort_t tl[DD][66];  // prep role only (+2 pad)
    int t = threadIdx.x;

    if (blockIdx.x < PACK_BLOCKS) {
        // ---------------- pack role: one wave per adj row ----------------
        int wave = (blockIdx.x * 256 + t) >> 6;   // global row 0..32767
        int lane = t & 63;
        const int* ap = adj + (size_t)wave * MM + lane * 4;
        int4 v[4];
        #pragma unroll
        for (int r = 0; r < 4; r++) v[r] = *(const int4*)(ap + r * 256);
        float2 x = *(const float2*)(h + (size_t)wave * DD + lane * 2);
        float2 a = *(const float2*)(a1 + lane * 2);
        float p = x.x * a.x + x.y * a.y;
        int cnt = 0;
        int sw = 2 * (wave & 15);                 // mask word swizzle key
        #pragma unroll
        for (int r = 0; r < 4; r++) {
            uint_t nib = (v[r].x > 0 ? 1u : 0u) | (v[r].y > 0 ? 2u : 0u)
                       | (v[r].z > 0 ? 4u : 0u) | (v[r].w > 0 ? 8u : 0u);
            cnt += __popc(nib);
            uint_t val = nib << (4 * (lane & 7));
            val |= __shfl_xor(val, 1);
            val |= __shfl_xor(val, 2);
            val |= __shfl_xor(val, 4);
            if ((lane & 7) == 0) {
                int w = r * 8 + (lane >> 3);      // word covers m=32w..32w+31
                maskw[(size_t)wave * 32 + (w ^ sw)] = val;
            }
        }
        #pragma unroll
        for (int s = 32; s; s >>= 1) {
            cnt += __shfl_xor(cnt, s);
            p   += __shfl_xor(p, s);
        }
        if (lane == 0) { degf[wave] = (float)cnt; e1[wave] = p; }
    } else {
        // ---------------- prep role: g transpose + e2 --------------------
        int bx = blockIdx.x - PACK_BLOCKS;
        int b = bx >> 4, m0 = (bx & 15) * 64;
        #pragma unroll
        for (int i = 0; i < 8; i++) {
            int idx = i * 256 + t;
            int m = idx >> 5;            // 32 consecutive lanes share row m
            int c4 = (idx & 31) * 4;
            float4 v = *(const float4*)(g + ((size_t)(b * MM + m0 + m)) * DD + c4);
            tl[c4 + 0][m] = (ushort_t)f2bf(v.x);
            tl[c4 + 1][m] = (ushort_t)f2bf(v.y);
            tl[c4 + 2][m] = (ushort_t)f2bf(v.z);
            tl[c4 + 3][m] = (ushort_t)f2bf(v.w);
            float4 av = *(const float4*)(a2 + c4);
            float p = v.x * av.x + v.y * av.y + v.z * av.z + v.w * av.w;
            #pragma unroll
            for (int s = 16; s; s >>= 1) p += __shfl_xor(p, s);
            if ((t & 31) == 0) e2[b * MM + m0 + m] = p;
        }
        __syncthreads();
        #pragma unroll
        for (int i = 0; i < 4; i++) {
            int idx = i * 256 + t;
            int d = idx >> 3;            // 0..127
            int c = (idx & 7) * 8;       // local m group
            int4 o;
            o.x = (int)((unsigned)tl[d][c + 0] | ((unsigned)tl[d][c + 1] << 16));
            o.y = (int)((unsigned)tl[d][c + 2] | ((unsigned)tl[d][c + 3] << 16));
            o.z = (int)((unsigned)tl[d][c + 4] | ((unsigned)tl[d][c + 5] << 16));
            o.w = (int)((unsigned)tl[d][c + 6] | ((unsigned)tl[d][c + 7] << 16));
            int mg = m0 + c;
            *(int4*)(gq + (((size_t)((b * 32 + (mg >> 5)) * DD + d)) << 5) + (mg & 31)) = o;
        }
    }
}

// ---- Kernel 2: softmax + PV; mask staged once, gq on ring-4 counted vmcnt ---
// block = 4 waves x 16 rows = 64 rows, all 128 d. In-loop HBM/L2 traffic is
// gq only (8 KB/chunk); mask tile (8 KB) DMA'd once at start.
__global__ __launch_bounds__(256, 2) void attn_tiled(
    const uint_t* __restrict__ maskw, const float* __restrict__ degf,
    const ushort_t* __restrict__ gq, const float* __restrict__ e1,
    const float* __restrict__ e2, float* __restrict__ out)
{
    __shared__ __align__(16) float e2S[MM];              // 4 KB
    __shared__ __align__(16) uint_t maskS[64 * 32];      // 8 KB
    __shared__ __align__(16) ushort_t gqS[4][128 * 32];  // 32 KB

    int b = blockIdx.y, n0 = blockIdx.x * 64, t = threadIdx.x;
    int wid = t >> 6, lane = t & 63;
    int rlo = lane & 15, hh = lane >> 4;
    int r = wid * 16 + rlo;          // block-local row 0..63

    // one-time staging: mask via DMA (linear), e2/e1/deg via VGPR loads
    const uint_t* mb = maskw + (size_t)(b * NN + n0) * 32;
    GLOAD16(mb + t * 4, &maskS[t * 4]);
    GLOAD16(mb + (t + 256) * 4, &maskS[(t + 256) * 4]);
    float4 ev = *(const float4*)(e2 + b * MM + t * 4);
    float e1f = L2E * e1[b * NN + n0 + r];
    float dgv = degf[b * NN + n0 + r];
    asm volatile("s_waitcnt vmcnt(0)" ::: "memory");
    ev.x *= L2E; ev.y *= L2E; ev.z *= L2E; ev.w *= L2E;
    *(float4*)(&e2S[t * 4]) = ev;
    __syncthreads();                 // mask+e2 visible; no DMA in flight

    const ushort_t* gqb = gq + (size_t)b * (32 * DD * 32);
    // gq staging: 512 slots = 128 d-rows x 4 slots of 8 shorts, src-swizzled
    int di0 = t, di1 = t + 256;
    int gd0 = di0 >> 2, gseg0 = (di0 & 3) ^ ((gd0 >> 1) & 3);
    int gd1 = di1 >> 2, gseg1 = (di1 & 3) ^ ((gd1 >> 1) & 3);

#define STAGE(P, K) do {                                                    \
        GLOAD16(gqb + (size_t)(K) * 4096 + gd0 * 32 + gseg0 * 8,            \
                &gqS[P][di0 * 8]);                                          \
        GLOAD16(gqb + (size_t)(K) * 4096 + gd1 * 32 + gseg1 * 8,            \
                &gqS[P][di1 * 8]);                                          \
    } while (0)

    f32x4 acc[8];
    #pragma unroll
    for (int j = 0; j < 8; j++) acc[j] = (f32x4){0.f, 0.f, 0.f, 0.f};
    float zl = 0.f;

#define COMPUTE(P, K) do {                                                  \
        uint_t mw = maskS[r * 32 + ((K) ^ (2 * rlo))];                      \
        uint_t mby = (mw >> (8 * hh)) & 0xffu;                              \
        float4 ev0 = *(const float4*)(&e2S[(K) * 32 + 8 * hh]);             \
        float4 ev1 = *(const float4*)(&e2S[(K) * 32 + 8 * hh + 4]);         \
        float ex[8] = {ev0.x, ev0.y, ev0.z, ev0.w,                          \
                       ev1.x, ev1.y, ev1.z, ev1.w};                         \
        bf16x8 af;                                                          \
        _Pragma("unroll")                                                   \
        for (int jj = 0; jj < 8; jj++) {                                    \
            float sp = e1f + ex[jj];                                        \
            float lk = fmaxf(sp, 0.2f * sp);                                \
            float sel = ((mby >> jj) & 1u) ? KEXP : 0.f;                    \
            float wv = sel * __builtin_amdgcn_exp2f(lk);                    \
            zl += wv;                                                       \
            af[jj] = (__bf16)wv;                                            \
        }                                                                   \
        _Pragma("unroll")                                                   \
        for (int j = 0; j < 8; j++) {                                       \
            int d = j * 16 + rlo;                                           \
            int4 bv = *(const int4*)(                                       \
                &gqS[P][d * 32 + (hh ^ ((rlo >> 1) & 3)) * 8]);             \
            acc[j] = __builtin_amdgcn_mfma_f32_16x16x32_bf16(               \
                         af, __builtin_bit_cast(bf16x8, bv), acc[j], 0,0,0);\
        }                                                                   \
    } while (0)

    // prologue: 3 stages in flight (6 DMA ops/thread)
    STAGE(0, 0); STAGE(1, 1); STAGE(2, 2);

    for (int k = 0; k < 30; ++k) {
        asm volatile("s_waitcnt vmcnt(4)" ::: "memory");  // stage k landed
        __builtin_amdgcn_s_barrier();                     // raw: no drain
        __builtin_amdgcn_sched_barrier(0);
        if (k < 29) STAGE((k + 3) & 3, k + 3);            // overwrites (k-1)&3
        COMPUTE(k & 3, k);
    }
    asm volatile("s_waitcnt vmcnt(2)" ::: "memory");      // stage 30 landed
    __builtin_amdgcn_s_barrier();
    __builtin_amdgcn_sched_barrier(0);
    COMPUTE(2, 30);
    asm volatile("s_waitcnt vmcnt(0)" ::: "memory");      // stage 31 landed
    __builtin_amdgcn_s_barrier();
    __builtin_amdgcn_sched_barrier(0);
    COMPUTE(3, 31);

#undef COMPUTE
#undef STAGE

    // per-row Z: lanes sharing rlo hold partials -> reduce lane bits 4,5.
    // KEXP cancels between acc (contains wv) and zl.
    zl += __shfl_xor(zl, 16); zl += __shfl_xor(zl, 32);
    float sc = (dgv > 0.f) ? (dgv / zl) : 0.f;           // = deg / Z

    float scr[4];
    #pragma unroll
    for (int rg = 0; rg < 4; rg++) scr[rg] = __shfl(sc, 4 * hh + rg);

    // C layout: col = rlo, row(within frag) = 4*hh + rg
    float* ob = out + ((size_t)(b * NN + n0 + wid * 16)) * DD + rlo;
    #pragma unroll
    for (int j = 0; j < 8; j++)
        #pragma unroll
        for (int rg = 0; rg < 4; rg++)
            ob[(size_t)(4 * hh + rg) * DD + j * 16] = acc[j][rg] * scr[rg];
}

extern "C" void kernel_launch(void* const* d_in, const int* in_sizes, int n_in,
                              void* d_out, int out_size, void* d_ws, size_t ws_size,
                              hipStream_t stream) {
    const float* h   = (const float*)d_in[0];
    const float* g   = (const float*)d_in[1];
    const int*   adj = (const int*)d_in[2];
    const float* a1  = (const float*)d_in[3];
    const float* a2  = (const float*)d_in[4];
    float* out = (float*)d_out;

    // workspace: e1 @0 (128 KB), e2 @128K (128 KB), degf @256K (128 KB),
    //            mask @384K (4 MB), gq @~4.4M (8 MB)
    char* ws = (char*)d_ws;
    float*    e1   = (float*)(ws);
    float*    e2   = (float*)(ws + (128u << 10));
    float*    degf = (float*)(ws + (256u << 10));
    uint_t*   mask = (uint_t*)(ws + (384u << 10));
    ushort_t* gq   = (ushort_t*)(ws + (384u << 10) + (4u << 20));

    pack_prep<<<dim3(PACK_BLOCKS + PREP_BLOCKS), 256, 0, stream>>>(
        adj, h, g, a1, a2, mask, degf, e1, gq, e2);
    attn_tiled<<<dim3(NN / 64, BB), 256, 0, stream>>>(mask, degf, gq, e1, e2, out);
}

// Round 17
// 48.150 us; speedup vs baseline: 1.2244x; 1.2244x over previous
//
#include <hip/hip_runtime.h>

#define BB 32
#define NN 1024
#define MM 1024
#define DD 128

typedef __attribute__((ext_vector_type(4))) float f32x4;
typedef __attribute__((ext_vector_type(8))) __bf16 bf16x8;
typedef unsigned short ushort_t;
typedef unsigned int uint_t;

#define L2E 1.44269504f

__device__ __forceinline__ unsigned f2bf(float x) {
    unsigned u = __builtin_bit_cast(unsigned, x);
    return (u + 0x7fffu + ((u >> 16) & 1u)) >> 16;  // RNE bf16, finite inputs
}

// async global->LDS, 16 B per lane; dest must be linear (base + lane*16)
#define GLOAD16(gp, lp)                                                     \
    __builtin_amdgcn_global_load_lds(                                       \
        (const __attribute__((address_space(1))) unsigned int*)(gp),        \
        (__attribute__((address_space(3))) unsigned int*)(lp), 16, 0, 0)

// ---- Kernel 1 (prep): gq = bf16(g)^T tiles ; e1 = h·a1 ;
//      e2B = exp(e2), e2D = exp(0.2*e2)  (factorized-softmax tables) ---------
__global__ __launch_bounds__(256) void prep(
    const float* __restrict__ g, const float* __restrict__ h,
    const float* __restrict__ a1, const float* __restrict__ a2,
    ushort_t* __restrict__ gq, float* __restrict__ e1,
    float* __restrict__ e2B, float* __restrict__ e2D)
{
    __shared__ ushort_t tl[DD][66];  // +2 pad breaks write bank conflicts
    int b = blockIdx.y, m0 = blockIdx.x * 64, t = threadIdx.x;

    #pragma unroll
    for (int i = 0; i < 8; i++) {
        int idx = i * 256 + t;
        int m = idx >> 5;            // 32 consecutive lanes share row m
        int c4 = (idx & 31) * 4;
        float4 v = *(const float4*)(h + ((size_t)(b * NN + m0 + m)) * DD + c4);
        float4 av = *(const float4*)(a1 + c4);
        float p = v.x * av.x + v.y * av.y + v.z * av.z + v.w * av.w;
        #pragma unroll
        for (int s = 16; s; s >>= 1) p += __shfl_xor(p, s);
        if ((t & 31) == 0) e1[b * NN + m0 + m] = p;
    }
    #pragma unroll
    for (int i = 0; i < 8; i++) {
        int idx = i * 256 + t;
        int m = idx >> 5;
        int c4 = (idx & 31) * 4;
        float4 v = *(const float4*)(g + ((size_t)(b * MM + m0 + m)) * DD + c4);
        tl[c4 + 0][m] = (ushort_t)f2bf(v.x);
        tl[c4 + 1][m] = (ushort_t)f2bf(v.y);
        tl[c4 + 2][m] = (ushort_t)f2bf(v.z);
        tl[c4 + 3][m] = (ushort_t)f2bf(v.w);
        float4 av = *(const float4*)(a2 + c4);
        float p = v.x * av.x + v.y * av.y + v.z * av.z + v.w * av.w;
        #pragma unroll
        for (int s = 16; s; s >>= 1) p += __shfl_xor(p, s);
        if ((t & 31) == 0) {
            e2B[b * MM + m0 + m] = __builtin_amdgcn_exp2f(L2E * p);
            e2D[b * MM + m0 + m] = __builtin_amdgcn_exp2f(0.2f * L2E * p);
        }
    }
    __syncthreads();
    #pragma unroll
    for (int i = 0; i < 4; i++) {
        int idx = i * 256 + t;
        int d = idx >> 3;            // 0..127
        int c = (idx & 7) * 8;       // local m group
        int4 o;
        o.x = (int)((unsigned)tl[d][c + 0] | ((unsigned)tl[d][c + 1] << 16));
        o.y = (int)((unsigned)tl[d][c + 2] | ((unsigned)tl[d][c + 3] << 16));
        o.z = (int)((unsigned)tl[d][c + 4] | ((unsigned)tl[d][c + 5] << 16));
        o.w = (int)((unsigned)tl[d][c + 6] | ((unsigned)tl[d][c + 7] << 16));
        int mg = m0 + c;
        *(int4*)(gq + (((size_t)((b * 32 + (mg >> 5)) * DD + d)) << 5) + (mg & 31)) = o;
    }
}

// ---- Kernel 2: fused adj+softmax+PV, ring-4 LDS, counted vmcnt (r13 base) ---
// Inner loop factorized: w = adj ? (B>invA ? B*A : D*C) : 0 — no exp, no leaky.
__global__ __launch_bounds__(256, 2) void attn_tiled(
    const int* __restrict__ adj, const ushort_t* __restrict__ gq,
    const float* __restrict__ e1, const float* __restrict__ e2B,
    const float* __restrict__ e2D, float* __restrict__ out)
{
    __shared__ __align__(16) float BfS[MM];             // 4 KB
    __shared__ __align__(16) float DfS[MM];             // 4 KB
    __shared__ __align__(16) int adjS[4][64 * 32];      // 4 x 8 KB
    __shared__ __align__(16) ushort_t gqS[4][128 * 32]; // 4 x 8 KB

    int b = blockIdx.y, n0 = blockIdx.x * 64, t = threadIdx.x;
    int wid = t >> 6, lane = t & 63;
    int rlo = lane & 15, hh = lane >> 4;
    int r = wid * 16 + rlo;          // block-local row 0..63
    int r8 = r & 7;

    // stage B/D tables
    *(float4*)(&BfS[t * 4]) = *(const float4*)(e2B + b * MM + t * 4);
    *(float4*)(&DfS[t * 4]) = *(const float4*)(e2D + b * MM + t * 4);
    float e1r = e1[b * NN + n0 + r];
    float An   = __builtin_amdgcn_exp2f(L2E * e1r);
    float Cn   = __builtin_amdgcn_exp2f(0.2f * L2E * e1r);
    float invA = __builtin_amdgcn_exp2f(-L2E * e1r);
    __syncthreads();                 // tables ready (no DMA in flight yet)

    const int* adjb = adj + (size_t)(b * NN + n0) * MM;
    const ushort_t* gqb = gq + (size_t)b * (32 * DD * 32);

    // adj staging: di in {t, t+256} covers 512 x 16B slots (64 rows x 8 slots),
    // source-swizzled seg = slot ^ (row&7)
    int adi0 = t, adi1 = t + 256;
    int arow0 = adi0 >> 3, aseg0 = (adi0 & 7) ^ (arow0 & 7);
    int arow1 = adi1 >> 3, aseg1 = (adi1 & 7) ^ (arow1 & 7);
    // gq staging: 512 slots = 128 d-rows x 4 slots of 8 shorts,
    // source-swizzled seg = slot ^ ((d>>1)&3)
    int gd0 = adi0 >> 2, gseg0 = (adi0 & 3) ^ ((gd0 >> 1) & 3);
    int gd1 = adi1 >> 2, gseg1 = (adi1 & 3) ^ ((gd1 >> 1) & 3);

#define STAGE(P, K) do {                                                    \
        GLOAD16(adjb + (size_t)arow0 * MM + (K) * 32 + aseg0 * 4,           \
                &adjS[P][adi0 * 4]);                                        \
        GLOAD16(adjb + (size_t)arow1 * MM + (K) * 32 + aseg1 * 4,           \
                &adjS[P][adi1 * 4]);                                        \
        GLOAD16(gqb + (size_t)(K) * 4096 + gd0 * 32 + gseg0 * 8,            \
                &gqS[P][adi0 * 8]);                                         \
        GLOAD16(gqb + (size_t)(K) * 4096 + gd1 * 32 + gseg1 * 8,            \
                &gqS[P][adi1 * 8]);                                         \
    } while (0)

    f32x4 acc[8];
    #pragma unroll
    for (int j = 0; j < 8; j++) acc[j] = (f32x4){0.f, 0.f, 0.f, 0.f};
    float zl = 0.f;
    int dcnt = 0;

#define COMPUTE(P, K) do {                                                  \
        int4 a0 = *(const int4*)(&adjS[P][r * 32 + ((2 * hh) ^ r8) * 4]);   \
        int4 a1 = *(const int4*)(&adjS[P][r * 32 + ((2 * hh + 1) ^ r8) * 4]);\
        float4 b0 = *(const float4*)(&BfS[(K) * 32 + 8 * hh]);              \
        float4 b1 = *(const float4*)(&BfS[(K) * 32 + 8 * hh + 4]);          \
        float4 d0 = *(const float4*)(&DfS[(K) * 32 + 8 * hh]);              \
        float4 d1 = *(const float4*)(&DfS[(K) * 32 + 8 * hh + 4]);          \
        float Bv[8] = {b0.x, b0.y, b0.z, b0.w, b1.x, b1.y, b1.z, b1.w};     \
        float Dv[8] = {d0.x, d0.y, d0.z, d0.w, d1.x, d1.y, d1.z, d1.w};     \
        int   ax[8] = {a0.x, a0.y, a0.z, a0.w, a1.x, a1.y, a1.z, a1.w};     \
        bf16x8 af;                                                          \
        _Pragma("unroll")                                                   \
        for (int jj = 0; jj < 8; jj++) {                                    \
            float val = (Bv[jj] > invA) ? Bv[jj] * An : Dv[jj] * Cn;        \
            float wv = (ax[jj] > 0) ? val : 0.f;                            \
            zl += wv;                                                       \
            dcnt += ax[jj];                                                 \
            af[jj] = (__bf16)wv;                                            \
        }                                                                   \
        _Pragma("unroll")                                                   \
        for (int j = 0; j < 8; j++) {                                       \
            int d = j * 16 + rlo;                                           \
            int4 bv = *(const int4*)(                                       \
                &gqS[P][d * 32 + (hh ^ ((rlo >> 1) & 3)) * 8]);             \
            acc[j] = __builtin_amdgcn_mfma_f32_16x16x32_bf16(               \
                         af, __builtin_bit_cast(bf16x8, bv), acc[j], 0,0,0);\
        }                                                                   \
    } while (0)

    // prologue: 3 stages in flight (12 DMA ops/thread)
    STAGE(0, 0); STAGE(1, 1); STAGE(2, 2);

    for (int k = 0; k < 30; ++k) {
        asm volatile("s_waitcnt vmcnt(8)" ::: "memory");  // stage k landed
        __builtin_amdgcn_s_barrier();                     // raw: no drain
        __builtin_amdgcn_sched_barrier(0);
        if (k < 29) STAGE((k + 3) & 3, k + 3);            // overwrites (k-1)&3
        COMPUTE(k & 3, k);
    }
    asm volatile("s_waitcnt vmcnt(4)" ::: "memory");      // stage 30 landed
    __builtin_amdgcn_s_barrier();
    __builtin_amdgcn_sched_barrier(0);
    COMPUTE(2, 30);
    asm volatile("s_waitcnt vmcnt(0)" ::: "memory");      // stage 31 landed
    __builtin_amdgcn_s_barrier();
    __builtin_amdgcn_sched_barrier(0);
    COMPUTE(3, 31);

#undef COMPUTE
#undef STAGE

    // per-row Z, deg: lanes sharing rlo hold partials -> reduce lane bits 4,5
    zl += __shfl_xor(zl, 16); zl += __shfl_xor(zl, 32);
    dcnt += __shfl_xor(dcnt, 16); dcnt += __shfl_xor(dcnt, 32);
    float sc = (dcnt > 0) ? ((float)dcnt / zl) : 0.f;    // = deg / Z

    float scr[4];
    #pragma unroll
    for (int rg = 0; rg < 4; rg++) scr[rg] = __shfl(sc, 4 * hh + rg);

    // C layout: col = rlo, row(within frag) = 4*hh + rg
    float* ob = out + ((size_t)(b * NN + n0 + wid * 16)) * DD + rlo;
    #pragma unroll
    for (int j = 0; j < 8; j++)
        #pragma unroll
        for (int rg = 0; rg < 4; rg++)
            ob[(size_t)(4 * hh + rg) * DD + j * 16] = acc[j][rg] * scr[rg];
}

extern "C" void kernel_launch(void* const* d_in, const int* in_sizes, int n_in,
                              void* d_out, int out_size, void* d_ws, size_t ws_size,
                              hipStream_t stream) {
    const float* h   = (const float*)d_in[0];
    const float* g   = (const float*)d_in[1];
    const int*   adj = (const int*)d_in[2];
    const float* a1  = (const float*)d_in[3];
    const float* a2  = (const float*)d_in[4];
    float* out = (float*)d_out;

    // workspace: e1 @0 (128 KB), e2B @128K (128 KB), e2D @256K (128 KB),
    //            gq @512K (8 MB)
    char* ws = (char*)d_ws;
    float*    e1  = (float*)(ws);
    float*    e2B = (float*)(ws + (128u << 10));
    float*    e2D = (float*)(ws + (256u << 10));
    ushort_t* gq  = (ushort_t*)(ws + (512u << 10));

    prep<<<dim3(MM / 64, BB), 256, 0, stream>>>(g, h, a1, a2, gq, e1, e2B, e2D);
    attn_tiled<<<dim3(NN / 64, BB), 256, 0, stream>>>(adj, gq, e1, e2B, e2D, out);
}